// Round 3
// baseline (594.194 us; speedup 1.0000x reference)
//
#include <hip/hip_runtime.h>
#include <hip/hip_bf16.h>

// VarianceAdaptor: 3x (conv1d->relu->LN->conv1d->relu->LN->linear) predictors,
// embedding adds between them, then length-regulate.
// Shapes fixed: B=32, S=512, D=F=512, K=3, T=4096, NB=256.
// Round 3: conv -> 2-phase double-buffered 256x128 tile (BK=64), grid=256
// blocks = 1/CU full chip, 8 waves. lin fused into LN2; topad fused into
// addemb. Exact fp32 path for x_out/mel_len unchanged.

#define B_ 32
#define S_ 512
#define D_ 512
#define F_ 512
#define T_ 4096
#define SP_ 514           // padded rows per batch (row0 and row513 are zeros)
#define KK_ 1536          // 3*512 contraction length
#define BM 256
#define BN 128
#define BKc 64
#define NKT 24            // 1536/64 K-tiles

typedef __attribute__((ext_vector_type(8))) short bf16x8;
typedef __attribute__((ext_vector_type(4))) float f32x4;

// ---------------- zero the pad rows of P (once per launch) -------------------
__global__ __launch_bounds__(128) void zeropad_k(__hip_bfloat16* __restrict__ P) {
  const int b = blockIdx.x >> 1;
  const int r = (blockIdx.x & 1) ? (SP_ - 1) : 0;
  *(ushort4*)((unsigned short*)P + ((size_t)b * SP_ + r) * D_ + threadIdx.x * 4) =
      make_ushort4(0, 0, 0, 0);
}

// ---------------- fp32 [B][512][512] -> bf16 padded P rows 1..512 ------------
__global__ __launch_bounds__(128) void topad_k(const float* __restrict__ in,
                                               __hip_bfloat16* __restrict__ P) {
  const int row = blockIdx.x;          // b*512 + s
  const int b = row >> 9, s = row & 511;
  const float4 v = *(const float4*)(in + (size_t)row * D_ + threadIdx.x * 4);
  __hip_bfloat16 h0 = __float2bfloat16(v.x), h1 = __float2bfloat16(v.y);
  __hip_bfloat16 h2 = __float2bfloat16(v.z), h3 = __float2bfloat16(v.w);
  ushort4 u = make_ushort4(*(unsigned short*)&h0, *(unsigned short*)&h1,
                           *(unsigned short*)&h2, *(unsigned short*)&h3);
  *(ushort4*)((unsigned short*)P + ((size_t)b * SP_ + s + 1) * D_ + threadIdx.x * 4) = u;
}

// ---------------- W [1536][512] fp32 -> WT [512][1536] bf16 (6 matrices) -----
__global__ __launch_bounds__(256) void wtrans_k(const float* __restrict__ W1,
                                                const float* __restrict__ W2,
                                                __hip_bfloat16* __restrict__ WT1,
                                                __hip_bfloat16* __restrict__ WT2) {
  __shared__ float tb[64][65];
  const int bid = blockIdx.x;          // w*192 + kt*8 + ft
  const int w = bid / 192;
  const int kt = (bid % 192) >> 3;     // 24 kk-tiles of 64
  const int ft = bid & 7;              // 8 f-tiles of 64
  const float* src = (w < 3) ? (W1 + (size_t)w * KK_ * F_)
                             : (W2 + (size_t)(w - 3) * KK_ * F_);
  __hip_bfloat16* dst = (w < 3) ? (WT1 + (size_t)w * KK_ * F_)
                                : (WT2 + (size_t)(w - 3) * KK_ * F_);
  const int ty = threadIdx.x >> 4, tx = threadIdx.x & 15;
  #pragma unroll
  for (int j = 0; j < 4; ++j) {
    const int r = ty + j * 16;         // kk within tile
    const float4 v = *(const float4*)(src + (size_t)(kt * 64 + r) * F_ + ft * 64 + tx * 4);
    tb[r][tx * 4 + 0] = v.x; tb[r][tx * 4 + 1] = v.y;
    tb[r][tx * 4 + 2] = v.z; tb[r][tx * 4 + 3] = v.w;
  }
  __syncthreads();
  #pragma unroll
  for (int j = 0; j < 4; ++j) {
    const int r = ty + j * 16;         // f within tile
    __hip_bfloat16 h0 = __float2bfloat16(tb[tx * 4 + 0][r]);
    __hip_bfloat16 h1 = __float2bfloat16(tb[tx * 4 + 1][r]);
    __hip_bfloat16 h2 = __float2bfloat16(tb[tx * 4 + 2][r]);
    __hip_bfloat16 h3 = __float2bfloat16(tb[tx * 4 + 3][r]);
    ushort4 u = make_ushort4(*(unsigned short*)&h0, *(unsigned short*)&h1,
                             *(unsigned short*)&h2, *(unsigned short*)&h3);
    *(ushort4*)((unsigned short*)dst + (size_t)(ft * 64 + r) * KK_ + kt * 64 + tx * 4) = u;
  }
}

// ---------------- conv as bf16 MFMA GEMM, 2-phase dbuf, 256x128 tile ---------
// Y[b*512+st+i][f0+j] = sum_{shift,d} P[b][st+shift+i][d] * WT[f0+j][shift*512+d]
__global__ __launch_bounds__(512) void convmm_k(const __hip_bfloat16* __restrict__ P,
                                                const __hip_bfloat16* __restrict__ WT,
                                                float* __restrict__ Y) {
  __shared__ __align__(16) __hip_bfloat16 As[2][BM * BKc];  // 32 KB x2
  __shared__ __align__(16) __hip_bfloat16 Bs[2][BN * BKc];  // 16 KB x2
  const int nt = blockIdx.x & 3;       // 4 N-tiles (f)
  const int mt = blockIdx.x >> 2;      // 64 M-tiles (rows)
  const int b  = mt >> 1;              // 2 M-tiles per batch
  const int st = (mt & 1) * BM;
  const int f0 = nt * BN;
  const int t = threadIdx.x;
  const int lane = t & 63;
  const int wave = t >> 6;
  const int wm = (wave >> 1) * 64;     // 4 M-waves x 2 N-waves, 64x64 each
  const int wn = (wave & 1) * 64;

  f32x4 acc[4][4];
  #pragma unroll
  for (int m = 0; m < 4; ++m)
    #pragma unroll
    for (int n = 0; n < 4; ++n) acc[m][n] = (f32x4){0.f, 0.f, 0.f, 0.f};

  const __hip_bfloat16* Xb = P + (size_t)b * SP_ * D_;

  auto stage = [&](int kt, int bufsel) {
    const int shift = kt >> 3;               // conv tap 0..2
    const int d0 = (kt & 7) * 64;            // d-tile within tap
    #pragma unroll
    for (int i = 0; i < 4; ++i) {            // A: 256x64 bf16 = 32KB = 2048 chunks
      const int c = t + i * 512;
      const int row = c >> 3, cg = (c & 7) * 8;
      const __hip_bfloat16* ga = Xb + (size_t)(st + shift + row) * D_ + d0 + cg;
      __builtin_amdgcn_global_load_lds(
          (const __attribute__((address_space(1))) void*)ga,
          (__attribute__((address_space(3))) void*)((char*)&As[bufsel][0] + c * 16),
          16, 0, 0);
    }
    #pragma unroll
    for (int i = 0; i < 2; ++i) {            // B: 128x64 bf16 = 16KB = 1024 chunks
      const int c = t + i * 512;
      const int fr = c >> 3, cg = (c & 7) * 8;
      const __hip_bfloat16* gb = WT + (size_t)(f0 + fr) * KK_ + shift * 512 + d0 + cg;
      __builtin_amdgcn_global_load_lds(
          (const __attribute__((address_space(1))) void*)gb,
          (__attribute__((address_space(3))) void*)((char*)&Bs[bufsel][0] + c * 16),
          16, 0, 0);
    }
  };

  stage(0, 0);
  __syncthreads();
  for (int kt = 0; kt < NKT; ++kt) {
    const int cur = kt & 1;
    if (kt < NKT - 1) stage(kt + 1, cur ^ 1);   // prefetch overlaps MFMA below
    const char* Ab = (const char*)&As[cur][0];
    const char* Bb = (const char*)&Bs[cur][0];
    const int rA = lane & 15;
    const int kg = (lane >> 4) * 16;            // 16B chunk within 64B k-half
    #pragma unroll
    for (int ks = 0; ks < 2; ++ks) {            // two K=32 MFMA steps per tile
      bf16x8 af[4], bfr[4];
      #pragma unroll
      for (int m = 0; m < 4; ++m)
        af[m] = *(const bf16x8*)(Ab + (wm + m * 16 + rA) * 128 + ks * 64 + kg);
      #pragma unroll
      for (int n = 0; n < 4; ++n)
        bfr[n] = *(const bf16x8*)(Bb + (wn + n * 16 + rA) * 128 + ks * 64 + kg);
      #pragma unroll
      for (int m = 0; m < 4; ++m)
        #pragma unroll
        for (int n = 0; n < 4; ++n)
          acc[m][n] = __builtin_amdgcn_mfma_f32_16x16x32_bf16(af[m], bfr[n], acc[m][n], 0, 0, 0);
    }
    __syncthreads();                            // drains prefetch; next buf ready
  }
  // C/D layout: col = lane&15, row = (lane>>4)*4 + reg   [m89-verified]
  const int col = lane & 15;
  const int r0 = (lane >> 4) * 4;
  #pragma unroll
  for (int m = 0; m < 4; ++m) {
    #pragma unroll
    for (int n = 0; n < 4; ++n) {
      float* yp = Y + ((size_t)b * S_ + st + wm + m * 16 + r0) * F_ + f0 + wn + n * 16 + col;
      #pragma unroll
      for (int r = 0; r < 4; ++r) yp[(size_t)r * F_] = acc[m][n][r];
    }
  }
}

// ------------- bias + relu + layernorm; fp32 in, bf16-padded out (into P) ----
__global__ __launch_bounds__(256) void ln_pad_k(const float* __restrict__ Y,
                                                const float* __restrict__ bias,
                                                const float* __restrict__ g,
                                                const float* __restrict__ be,
                                                __hip_bfloat16* __restrict__ P) {
  const int row = blockIdx.x;          // b*512 + s
  const int t   = threadIdx.x;
  const float* p = Y + (size_t)row * F_;
  float2 v = *(const float2*)(p + t * 2);
  v.x = fmaxf(v.x + bias[t * 2], 0.f);
  v.y = fmaxf(v.y + bias[t * 2 + 1], 0.f);
  __shared__ float red[6];
  float s = v.x + v.y;
  #pragma unroll
  for (int o = 32; o > 0; o >>= 1) s += __shfl_down(s, o, 64);
  const int lane = t & 63, w = t >> 6;
  if (lane == 0) red[w] = s;
  __syncthreads();
  if (t == 0) red[4] = red[0] + red[1] + red[2] + red[3];
  __syncthreads();
  const float mean = red[4] * (1.f / F_);
  const float dx = v.x - mean, dy = v.y - mean;
  float q = dx * dx + dy * dy;
  #pragma unroll
  for (int o = 32; o > 0; o >>= 1) q += __shfl_down(q, o, 64);
  __syncthreads();
  if (lane == 0) red[w] = q;
  __syncthreads();
  if (t == 0) red[5] = red[0] + red[1] + red[2] + red[3];
  __syncthreads();
  const float inv = rsqrtf(red[5] * (1.f / F_) + 1e-5f);
  __hip_bfloat16 h0 = __float2bfloat16(dx * inv * g[t * 2]     + be[t * 2]);
  __hip_bfloat16 h1 = __float2bfloat16(dy * inv * g[t * 2 + 1] + be[t * 2 + 1]);
  ushort2 u = make_ushort2(*(unsigned short*)&h0, *(unsigned short*)&h1);
  const int b = row >> 9, sr = row & 511;
  *(ushort2*)((unsigned short*)P + ((size_t)b * SP_ + sr + 1) * D_ + t * 2) = u;
}

// ------------- bias + relu + LN + fused linear head: pred only, no y write ---
__global__ __launch_bounds__(256) void lnlin_k(const float* __restrict__ Y,
                                               const float* __restrict__ bias,
                                               const float* __restrict__ g,
                                               const float* __restrict__ be,
                                               const float* __restrict__ wl,
                                               const float* __restrict__ bl,
                                               const unsigned char* __restrict__ mask,
                                               float* __restrict__ pred) {
  const int row = blockIdx.x;
  const int t   = threadIdx.x;
  const float* p = Y + (size_t)row * F_;
  float2 v = *(const float2*)(p + t * 2);
  v.x = fmaxf(v.x + bias[t * 2], 0.f);
  v.y = fmaxf(v.y + bias[t * 2 + 1], 0.f);
  __shared__ float red[6];
  float s = v.x + v.y;
  #pragma unroll
  for (int o = 32; o > 0; o >>= 1) s += __shfl_down(s, o, 64);
  const int lane = t & 63, w = t >> 6;
  if (lane == 0) red[w] = s;
  __syncthreads();
  if (t == 0) red[4] = red[0] + red[1] + red[2] + red[3];
  __syncthreads();
  const float mean = red[4] * (1.f / F_);
  const float dx = v.x - mean, dy = v.y - mean;
  float q = dx * dx + dy * dy;
  #pragma unroll
  for (int o = 32; o > 0; o >>= 1) q += __shfl_down(q, o, 64);
  __syncthreads();
  if (lane == 0) red[w] = q;
  __syncthreads();
  if (t == 0) red[5] = red[0] + red[1] + red[2] + red[3];
  __syncthreads();
  const float inv = rsqrtf(red[5] * (1.f / F_) + 1e-5f);
  const float ox = dx * inv * g[t * 2]     + be[t * 2];
  const float oy = dy * inv * g[t * 2 + 1] + be[t * 2 + 1];
  float dp = ox * wl[t * 2] + oy * wl[t * 2 + 1];
  #pragma unroll
  for (int o = 32; o > 0; o >>= 1) dp += __shfl_down(dp, o, 64);
  if (lane == 0) red[w] = dp;          // red[0..3] free to reuse here
  __syncthreads();
  if (t == 0)
    pred[row] = mask[row] ? 0.f : (red[0] + red[1] + red[2] + red[3] + bl[0]);
}

// ----- out[row,:] = in[row,:] + emb[idx]; also write bf16 into padded P ------
__global__ __launch_bounds__(128) void addembP_k(const float* __restrict__ in,
                                                 const float* __restrict__ truth,
                                                 const float* __restrict__ bins,
                                                 const float* __restrict__ emb,
                                                 float* __restrict__ out,
                                                 __hip_bfloat16* __restrict__ P) {
  const int row = blockIdx.x;  // b*S + s
  __shared__ int sidx;
  if (threadIdx.x == 0) {
    const float v = truth[row];
    int lo = 0, hi = 255;  // NB-1 bins
    while (lo < hi) {
      const int mid = (lo + hi) >> 1;
      if (bins[mid] < v) lo = mid + 1; else hi = mid;
    }
    sidx = lo;  // #{bins < v} == searchsorted side='left'
  }
  __syncthreads();
  const int e = sidx;
  float4 a = *(const float4*)(in + (size_t)row * D_ + threadIdx.x * 4);
  const float4 b4 = *(const float4*)(emb + (size_t)e * D_ + threadIdx.x * 4);
  a.x += b4.x; a.y += b4.y; a.z += b4.z; a.w += b4.w;
  *(float4*)(out + (size_t)row * D_ + threadIdx.x * 4) = a;
  __hip_bfloat16 h0 = __float2bfloat16(a.x), h1 = __float2bfloat16(a.y);
  __hip_bfloat16 h2 = __float2bfloat16(a.z), h3 = __float2bfloat16(a.w);
  ushort4 u = make_ushort4(*(unsigned short*)&h0, *(unsigned short*)&h1,
                           *(unsigned short*)&h2, *(unsigned short*)&h3);
  const int b = row >> 9, s = row & 511;
  *(ushort4*)((unsigned short*)P + ((size_t)b * SP_ + s + 1) * D_ + threadIdx.x * 4) = u;
}

// ------------- inclusive cumsum of durations per batch; mel_len as float -----
__global__ __launch_bounds__(512) void scan_k(const int* __restrict__ dur,
                                              int* __restrict__ cum,
                                              float* __restrict__ mel_len) {
  __shared__ int sh[S_];
  const int b = blockIdx.x, t = threadIdx.x;
  sh[t] = dur[b * S_ + t];
  __syncthreads();
  for (int off = 1; off < S_; off <<= 1) {
    const int add = (t >= off) ? sh[t - off] : 0;
    __syncthreads();
    sh[t] += add;
    __syncthreads();
  }
  cum[b * S_ + t] = sh[t];
  if (t == S_ - 1) mel_len[b] = (float)sh[t];
}

// ------------- length regulate: out[b,pos,:] = valid ? x[b,idx,:] : 0 --------
__global__ __launch_bounds__(128) void gather_k(const float* __restrict__ X,
                                                const int* __restrict__ cum,
                                                float* __restrict__ out) {
  const int b   = blockIdx.x >> 12;    // T=4096 positions per batch
  const int pos = blockIdx.x & (T_ - 1);
  __shared__ int sidx, svalid;
  if (threadIdx.x == 0) {
    const int* c = cum + b * S_;
    int lo = 0, hi = S_;
    while (lo < hi) {                  // upper_bound: first c[i] > pos
      const int mid = (lo + hi) >> 1;
      if (c[mid] <= pos) lo = mid + 1; else hi = mid;
    }
    sidx = (lo < S_ - 1) ? lo : (S_ - 1);
    svalid = (pos < c[S_ - 1]) ? 1 : 0;
  }
  __syncthreads();
  float4 v = make_float4(0.f, 0.f, 0.f, 0.f);
  if (svalid) v = *(const float4*)(X + ((size_t)b * S_ + sidx) * D_ + threadIdx.x * 4);
  *(float4*)(out + ((size_t)b * T_ + pos) * D_ + threadIdx.x * 4) = v;
}

// ------------- mel_mask bool -> float ---------------------------------------
__global__ __launch_bounds__(256) void maskcopy_k(const unsigned char* __restrict__ m,
                                                  float* __restrict__ out) {
  const int i = blockIdx.x * 256 + threadIdx.x;
  out[i] = m[i] ? 1.f : 0.f;
}

extern "C" void kernel_launch(void* const* d_in, const int* in_sizes, int n_in,
                              void* d_out, int out_size, void* d_ws, size_t ws_size,
                              hipStream_t stream) {
  const float* x            = (const float*)d_in[0];
  const unsigned char* srcm = (const unsigned char*)d_in[1];
  const unsigned char* melm = (const unsigned char*)d_in[2];
  const float* pitch_truth  = (const float*)d_in[3];
  const float* energy_truth = (const float*)d_in[4];
  const int*   dur          = (const int*)d_in[5];
  const float* conv1_w = (const float*)d_in[6];
  const float* conv1_b = (const float*)d_in[7];
  const float* ln1_g   = (const float*)d_in[8];
  const float* ln1_b   = (const float*)d_in[9];
  const float* conv2_w = (const float*)d_in[10];
  const float* conv2_b = (const float*)d_in[11];
  const float* ln2_g   = (const float*)d_in[12];
  const float* ln2_b   = (const float*)d_in[13];
  const float* lin_w   = (const float*)d_in[14];
  const float* lin_b   = (const float*)d_in[15];
  const float* pitch_emb   = (const float*)d_in[16];
  const float* energy_emb  = (const float*)d_in[17];
  const float* pitch_bins  = (const float*)d_in[18];
  const float* energy_bins = (const float*)d_in[19];

  float* out      = (float*)d_out;
  float* x_out    = out;                               // 32*4096*512
  float* p_pitch  = out + (size_t)B_ * T_ * D_;
  float* p_energy = p_pitch + B_ * S_;
  float* p_dur    = p_energy + B_ * S_;
  float* p_mellen = p_dur + B_ * S_;
  float* p_mask   = p_mellen + B_;

  // ws: P (16.8MB bf16 padded) | WT1 (4.7MB) | WT2 (4.7MB) | y (33.6MB f32)
  //     | xa (33.6MB f32) | cum (64KB)   total ~93.5MB
  __hip_bfloat16* P   = (__hip_bfloat16*)d_ws;
  __hip_bfloat16* WT1 = P + (size_t)B_ * SP_ * D_;
  __hip_bfloat16* WT2 = WT1 + (size_t)3 * F_ * KK_;
  float* y  = (float*)(WT2 + (size_t)3 * F_ * KK_);
  float* xa = y + (size_t)B_ * S_ * F_;
  int*  cum = (int*)(xa + (size_t)B_ * S_ * D_);

  const dim3 blk512t(512), blk256(256), blk128(128);
  const dim3 rowGrid(B_ * S_);               // 16384
  const dim3 convGrid(64 * 4);               // 64 M-tiles x 4 N-tiles = 256

  zeropad_k<<<dim3(B_ * 2), blk128, 0, stream>>>(P);
  wtrans_k<<<dim3(6 * 24 * 8), blk256, 0, stream>>>(conv1_w, conv2_w, WT1, WT2);
  topad_k<<<rowGrid, blk128, 0, stream>>>(x, P);

  auto predictor = [&](int i, float* pred) {
    convmm_k<<<convGrid, blk512t, 0, stream>>>(P, WT1 + (size_t)i * F_ * KK_, y);
    ln_pad_k<<<rowGrid, blk256, 0, stream>>>(y, conv1_b + (size_t)i * F_,
                                             ln1_g + (size_t)i * F_,
                                             ln1_b + (size_t)i * F_, P);
    convmm_k<<<convGrid, blk512t, 0, stream>>>(P, WT2 + (size_t)i * F_ * KK_, y);
    lnlin_k<<<rowGrid, blk256, 0, stream>>>(y, conv2_b + (size_t)i * F_,
                                            ln2_g + (size_t)i * F_,
                                            ln2_b + (size_t)i * F_,
                                            lin_w + (size_t)i * F_, lin_b + i,
                                            srcm, pred);
  };

  predictor(0, p_pitch);
  addembP_k<<<rowGrid, blk128, 0, stream>>>(x, pitch_truth, pitch_bins, pitch_emb, xa, P);
  predictor(1, p_energy);
  addembP_k<<<rowGrid, blk128, 0, stream>>>(xa, energy_truth, energy_bins, energy_emb, xa, P);
  predictor(2, p_dur);

  scan_k<<<dim3(B_), blk512t, 0, stream>>>(dur, cum, p_mellen);
  gather_k<<<dim3(B_ * T_), blk128, 0, stream>>>(xa, cum, x_out);
  maskcopy_k<<<dim3((B_ * T_) / 256), blk256, 0, stream>>>(melm, p_mask);
}

// Round 4
// 490.885 us; speedup vs baseline: 1.2105x; 1.2105x over previous
//
#include <hip/hip_runtime.h>
#include <hip/hip_bf16.h>

// VarianceAdaptor: 3x (conv1d->relu->LN->conv1d->relu->LN->linear) predictors,
// embedding adds between them, then length-regulate.
// Shapes fixed: B=32, S=512, D=F=512, K=3, T=4096, NB=256.
// Round 4: conv reverted to R2 geometry (128^2 tile, 4 waves, grid=512 =
// 2 blocks/CU — sibling block covers barrier drain; R3's 1/CU regressed).
// Conv output Y now bf16 (LN renormalizes; halves store+LN-read traffic).
// Fusions kept: lin folded into LN2, topad folded into addemb.

#define B_ 32
#define S_ 512
#define D_ 512
#define F_ 512
#define T_ 4096
#define SP_ 514           // padded rows per batch (row0 and row513 are zeros)
#define KK_ 1536          // 3*512 contraction length

typedef __attribute__((ext_vector_type(8))) short bf16x8;
typedef __attribute__((ext_vector_type(4))) float f32x4;

__device__ __forceinline__ float bf2f(unsigned short u) {
  union { unsigned int i; float f; } c; c.i = (unsigned int)u << 16; return c.f;
}

// ---------------- zero the pad rows of P (once per launch) -------------------
__global__ __launch_bounds__(128) void zeropad_k(__hip_bfloat16* __restrict__ P) {
  const int b = blockIdx.x >> 1;
  const int r = (blockIdx.x & 1) ? (SP_ - 1) : 0;
  *(ushort4*)((unsigned short*)P + ((size_t)b * SP_ + r) * D_ + threadIdx.x * 4) =
      make_ushort4(0, 0, 0, 0);
}

// ---------------- fp32 [B][512][512] -> bf16 padded P rows 1..512 ------------
__global__ __launch_bounds__(128) void topad_k(const float* __restrict__ in,
                                               __hip_bfloat16* __restrict__ P) {
  const int row = blockIdx.x;          // b*512 + s
  const int b = row >> 9, s = row & 511;
  const float4 v = *(const float4*)(in + (size_t)row * D_ + threadIdx.x * 4);
  __hip_bfloat16 h0 = __float2bfloat16(v.x), h1 = __float2bfloat16(v.y);
  __hip_bfloat16 h2 = __float2bfloat16(v.z), h3 = __float2bfloat16(v.w);
  ushort4 u = make_ushort4(*(unsigned short*)&h0, *(unsigned short*)&h1,
                           *(unsigned short*)&h2, *(unsigned short*)&h3);
  *(ushort4*)((unsigned short*)P + ((size_t)b * SP_ + s + 1) * D_ + threadIdx.x * 4) = u;
}

// ---------------- W [1536][512] fp32 -> WT [512][1536] bf16 (6 matrices) -----
__global__ __launch_bounds__(256) void wtrans_k(const float* __restrict__ W1,
                                                const float* __restrict__ W2,
                                                __hip_bfloat16* __restrict__ WT1,
                                                __hip_bfloat16* __restrict__ WT2) {
  __shared__ float tb[64][65];
  const int bid = blockIdx.x;          // w*192 + kt*8 + ft
  const int w = bid / 192;
  const int kt = (bid % 192) >> 3;     // 24 kk-tiles of 64
  const int ft = bid & 7;              // 8 f-tiles of 64
  const float* src = (w < 3) ? (W1 + (size_t)w * KK_ * F_)
                             : (W2 + (size_t)(w - 3) * KK_ * F_);
  __hip_bfloat16* dst = (w < 3) ? (WT1 + (size_t)w * KK_ * F_)
                                : (WT2 + (size_t)(w - 3) * KK_ * F_);
  const int ty = threadIdx.x >> 4, tx = threadIdx.x & 15;
  #pragma unroll
  for (int j = 0; j < 4; ++j) {
    const int r = ty + j * 16;         // kk within tile
    const float4 v = *(const float4*)(src + (size_t)(kt * 64 + r) * F_ + ft * 64 + tx * 4);
    tb[r][tx * 4 + 0] = v.x; tb[r][tx * 4 + 1] = v.y;
    tb[r][tx * 4 + 2] = v.z; tb[r][tx * 4 + 3] = v.w;
  }
  __syncthreads();
  #pragma unroll
  for (int j = 0; j < 4; ++j) {
    const int r = ty + j * 16;         // f within tile
    __hip_bfloat16 h0 = __float2bfloat16(tb[tx * 4 + 0][r]);
    __hip_bfloat16 h1 = __float2bfloat16(tb[tx * 4 + 1][r]);
    __hip_bfloat16 h2 = __float2bfloat16(tb[tx * 4 + 2][r]);
    __hip_bfloat16 h3 = __float2bfloat16(tb[tx * 4 + 3][r]);
    ushort4 u = make_ushort4(*(unsigned short*)&h0, *(unsigned short*)&h1,
                             *(unsigned short*)&h2, *(unsigned short*)&h3);
    *(ushort4*)((unsigned short*)dst + (size_t)(ft * 64 + r) * KK_ + kt * 64 + tx * 4) = u;
  }
}

// ---------------- conv as bf16 MFMA GEMM (R2/m97 structure, bf16 out) --------
// Y[b*512+st+i][f0+j] = sum_{shift,d} P[b][st+shift+i][d] * WT[f0+j][shift*512+d]
__global__ __launch_bounds__(256) void convmm_k(const __hip_bfloat16* __restrict__ P,
                                                const __hip_bfloat16* __restrict__ WT,
                                                __hip_bfloat16* __restrict__ Yb) {
  __shared__ __align__(16) __hip_bfloat16 As[128 * 32];  // 8 KB  [row][k]
  __shared__ __align__(16) __hip_bfloat16 Bs[128 * 32];  // 8 KB  [f][k]
  const int nt = blockIdx.x & 3;       // 4 N-tiles (f)
  const int mt = blockIdx.x >> 2;      // 128 M-tiles (rows)
  const int b  = mt >> 2;              // 4 M-tiles per batch
  const int st = (mt & 3) * 128;
  const int f0 = nt * 128;
  const int t = threadIdx.x;
  const int lane = t & 63;
  const int wave = t >> 6;
  const int wm = (wave >> 1) * 64;     // 2x2 wave grid, 64x64 each
  const int wn = (wave & 1) * 64;

  f32x4 acc[4][4];
  #pragma unroll
  for (int m = 0; m < 4; ++m)
    #pragma unroll
    for (int n = 0; n < 4; ++n) acc[m][n] = (f32x4){0.f, 0.f, 0.f, 0.f};

  const __hip_bfloat16* Xb = P + (size_t)b * SP_ * D_;
  const int slot0 = wave * 64 + lane;

  for (int kk = 0; kk < 48; ++kk) {
    const int shift = kk >> 4;               // 0..2 (conv tap)
    const int d0 = (kk & 15) * 32;           // d-tile
    const int kb = shift * 512 + d0;         // kk base for WT
    #pragma unroll
    for (int j = 0; j < 2; ++j) {
      const int slot = j * 256 + slot0;      // 512 slots of 16B per tile
      const int row = slot >> 2, cg = (slot & 3) * 8;
      const __hip_bfloat16* ga = Xb + (size_t)(st + shift + row) * D_ + d0 + cg;
      __builtin_amdgcn_global_load_lds(
          (const __attribute__((address_space(1))) void*)ga,
          (__attribute__((address_space(3))) void*)((char*)As + (j * 256 + wave * 64) * 16),
          16, 0, 0);
      const __hip_bfloat16* gb = WT + (size_t)(f0 + row) * KK_ + kb + cg;
      __builtin_amdgcn_global_load_lds(
          (const __attribute__((address_space(1))) void*)gb,
          (__attribute__((address_space(3))) void*)((char*)Bs + (j * 256 + wave * 64) * 16),
          16, 0, 0);
    }
    __syncthreads();
    const int rA = lane & 15;
    const int kc = (lane >> 4) * 16;         // byte offset of 8-elem K-chunk
    bf16x8 af[4], bfr[4];
    #pragma unroll
    for (int m = 0; m < 4; ++m)
      af[m] = *(const bf16x8*)((const char*)As + (wm + m * 16 + rA) * 64 + kc);
    #pragma unroll
    for (int n = 0; n < 4; ++n)
      bfr[n] = *(const bf16x8*)((const char*)Bs + (wn + n * 16 + rA) * 64 + kc);
    #pragma unroll
    for (int m = 0; m < 4; ++m)
      #pragma unroll
      for (int n = 0; n < 4; ++n)
        acc[m][n] = __builtin_amdgcn_mfma_f32_16x16x32_bf16(af[m], bfr[n], acc[m][n], 0, 0, 0);
    __syncthreads();
  }
  // C/D layout: col = lane&15, row = (lane>>4)*4 + reg   [m89-verified]
  const int col = lane & 15;
  const int r0 = (lane >> 4) * 4;
  unsigned short* Yu = (unsigned short*)Yb;
  #pragma unroll
  for (int m = 0; m < 4; ++m) {
    #pragma unroll
    for (int n = 0; n < 4; ++n) {
      unsigned short* yp =
          Yu + ((size_t)b * S_ + st + wm + m * 16 + r0) * F_ + f0 + wn + n * 16 + col;
      #pragma unroll
      for (int r = 0; r < 4; ++r) {
        __hip_bfloat16 h = __float2bfloat16(acc[m][n][r]);
        yp[(size_t)r * F_] = *(unsigned short*)&h;
      }
    }
  }
}

// ------------- bias + relu + layernorm; bf16 in, bf16-padded out (into P) ----
__global__ __launch_bounds__(256) void ln_pad_k(const __hip_bfloat16* __restrict__ Yb,
                                                const float* __restrict__ bias,
                                                const float* __restrict__ g,
                                                const float* __restrict__ be,
                                                __hip_bfloat16* __restrict__ P) {
  const int row = blockIdx.x;          // b*512 + s
  const int t   = threadIdx.x;
  const ushort2 u2 = *(const ushort2*)((const unsigned short*)Yb + (size_t)row * F_ + t * 2);
  float2 v = make_float2(bf2f(u2.x), bf2f(u2.y));
  v.x = fmaxf(v.x + bias[t * 2], 0.f);
  v.y = fmaxf(v.y + bias[t * 2 + 1], 0.f);
  __shared__ float red[6];
  float s = v.x + v.y;
  #pragma unroll
  for (int o = 32; o > 0; o >>= 1) s += __shfl_down(s, o, 64);
  const int lane = t & 63, w = t >> 6;
  if (lane == 0) red[w] = s;
  __syncthreads();
  if (t == 0) red[4] = red[0] + red[1] + red[2] + red[3];
  __syncthreads();
  const float mean = red[4] * (1.f / F_);
  const float dx = v.x - mean, dy = v.y - mean;
  float q = dx * dx + dy * dy;
  #pragma unroll
  for (int o = 32; o > 0; o >>= 1) q += __shfl_down(q, o, 64);
  __syncthreads();
  if (lane == 0) red[w] = q;
  __syncthreads();
  if (t == 0) red[5] = red[0] + red[1] + red[2] + red[3];
  __syncthreads();
  const float inv = rsqrtf(red[5] * (1.f / F_) + 1e-5f);
  __hip_bfloat16 h0 = __float2bfloat16(dx * inv * g[t * 2]     + be[t * 2]);
  __hip_bfloat16 h1 = __float2bfloat16(dy * inv * g[t * 2 + 1] + be[t * 2 + 1]);
  ushort2 u = make_ushort2(*(unsigned short*)&h0, *(unsigned short*)&h1);
  const int b = row >> 9, sr = row & 511;
  *(ushort2*)((unsigned short*)P + ((size_t)b * SP_ + sr + 1) * D_ + t * 2) = u;
}

// ------------- bias + relu + LN + fused linear head: pred only, no y write ---
__global__ __launch_bounds__(256) void lnlin_k(const __hip_bfloat16* __restrict__ Yb,
                                               const float* __restrict__ bias,
                                               const float* __restrict__ g,
                                               const float* __restrict__ be,
                                               const float* __restrict__ wl,
                                               const float* __restrict__ bl,
                                               const unsigned char* __restrict__ mask,
                                               float* __restrict__ pred) {
  const int row = blockIdx.x;
  const int t   = threadIdx.x;
  const ushort2 u2 = *(const ushort2*)((const unsigned short*)Yb + (size_t)row * F_ + t * 2);
  float2 v = make_float2(bf2f(u2.x), bf2f(u2.y));
  v.x = fmaxf(v.x + bias[t * 2], 0.f);
  v.y = fmaxf(v.y + bias[t * 2 + 1], 0.f);
  __shared__ float red[6];
  float s = v.x + v.y;
  #pragma unroll
  for (int o = 32; o > 0; o >>= 1) s += __shfl_down(s, o, 64);
  const int lane = t & 63, w = t >> 6;
  if (lane == 0) red[w] = s;
  __syncthreads();
  if (t == 0) red[4] = red[0] + red[1] + red[2] + red[3];
  __syncthreads();
  const float mean = red[4] * (1.f / F_);
  const float dx = v.x - mean, dy = v.y - mean;
  float q = dx * dx + dy * dy;
  #pragma unroll
  for (int o = 32; o > 0; o >>= 1) q += __shfl_down(q, o, 64);
  __syncthreads();
  if (lane == 0) red[w] = q;
  __syncthreads();
  if (t == 0) red[5] = red[0] + red[1] + red[2] + red[3];
  __syncthreads();
  const float inv = rsqrtf(red[5] * (1.f / F_) + 1e-5f);
  const float ox = dx * inv * g[t * 2]     + be[t * 2];
  const float oy = dy * inv * g[t * 2 + 1] + be[t * 2 + 1];
  float dp = ox * wl[t * 2] + oy * wl[t * 2 + 1];
  #pragma unroll
  for (int o = 32; o > 0; o >>= 1) dp += __shfl_down(dp, o, 64);
  if (lane == 0) red[w] = dp;          // red[0..3] reuse; no reader of 4/5 left
  __syncthreads();
  if (t == 0)
    pred[row] = mask[row] ? 0.f : (red[0] + red[1] + red[2] + red[3] + bl[0]);
}

// ----- out[row,:] = in[row,:] + emb[idx]; also write bf16 into padded P ------
__global__ __launch_bounds__(128) void addembP_k(const float* __restrict__ in,
                                                 const float* __restrict__ truth,
                                                 const float* __restrict__ bins,
                                                 const float* __restrict__ emb,
                                                 float* __restrict__ out,
                                                 __hip_bfloat16* __restrict__ P) {
  const int row = blockIdx.x;  // b*S + s
  __shared__ int sidx;
  if (threadIdx.x == 0) {
    const float v = truth[row];
    int lo = 0, hi = 255;  // NB-1 bins
    while (lo < hi) {
      const int mid = (lo + hi) >> 1;
      if (bins[mid] < v) lo = mid + 1; else hi = mid;
    }
    sidx = lo;  // #{bins < v} == searchsorted side='left'
  }
  __syncthreads();
  const int e = sidx;
  float4 a = *(const float4*)(in + (size_t)row * D_ + threadIdx.x * 4);
  const float4 b4 = *(const float4*)(emb + (size_t)e * D_ + threadIdx.x * 4);
  a.x += b4.x; a.y += b4.y; a.z += b4.z; a.w += b4.w;
  *(float4*)(out + (size_t)row * D_ + threadIdx.x * 4) = a;
  __hip_bfloat16 h0 = __float2bfloat16(a.x), h1 = __float2bfloat16(a.y);
  __hip_bfloat16 h2 = __float2bfloat16(a.z), h3 = __float2bfloat16(a.w);
  ushort4 u = make_ushort4(*(unsigned short*)&h0, *(unsigned short*)&h1,
                           *(unsigned short*)&h2, *(unsigned short*)&h3);
  const int b = row >> 9, s = row & 511;
  *(ushort4*)((unsigned short*)P + ((size_t)b * SP_ + s + 1) * D_ + threadIdx.x * 4) = u;
}

// ------------- inclusive cumsum of durations per batch; mel_len as float -----
__global__ __launch_bounds__(512) void scan_k(const int* __restrict__ dur,
                                              int* __restrict__ cum,
                                              float* __restrict__ mel_len) {
  __shared__ int sh[S_];
  const int b = blockIdx.x, t = threadIdx.x;
  sh[t] = dur[b * S_ + t];
  __syncthreads();
  for (int off = 1; off < S_; off <<= 1) {
    const int add = (t >= off) ? sh[t - off] : 0;
    __syncthreads();
    sh[t] += add;
    __syncthreads();
  }
  cum[b * S_ + t] = sh[t];
  if (t == S_ - 1) mel_len[b] = (float)sh[t];
}

// ------------- length regulate: out[b,pos,:] = valid ? x[b,idx,:] : 0 --------
__global__ __launch_bounds__(128) void gather_k(const float* __restrict__ X,
                                                const int* __restrict__ cum,
                                                float* __restrict__ out) {
  const int b   = blockIdx.x >> 12;    // T=4096 positions per batch
  const int pos = blockIdx.x & (T_ - 1);
  __shared__ int sidx, svalid;
  if (threadIdx.x == 0) {
    const int* c = cum + b * S_;
    int lo = 0, hi = S_;
    while (lo < hi) {                  // upper_bound: first c[i] > pos
      const int mid = (lo + hi) >> 1;
      if (c[mid] <= pos) lo = mid + 1; else hi = mid;
    }
    sidx = (lo < S_ - 1) ? lo : (S_ - 1);
    svalid = (pos < c[S_ - 1]) ? 1 : 0;
  }
  __syncthreads();
  float4 v = make_float4(0.f, 0.f, 0.f, 0.f);
  if (svalid) v = *(const float4*)(X + ((size_t)b * S_ + sidx) * D_ + threadIdx.x * 4);
  *(float4*)(out + ((size_t)b * T_ + pos) * D_ + threadIdx.x * 4) = v;
}

// ------------- mel_mask bool -> float ---------------------------------------
__global__ __launch_bounds__(256) void maskcopy_k(const unsigned char* __restrict__ m,
                                                  float* __restrict__ out) {
  const int i = blockIdx.x * 256 + threadIdx.x;
  out[i] = m[i] ? 1.f : 0.f;
}

extern "C" void kernel_launch(void* const* d_in, const int* in_sizes, int n_in,
                              void* d_out, int out_size, void* d_ws, size_t ws_size,
                              hipStream_t stream) {
  const float* x            = (const float*)d_in[0];
  const unsigned char* srcm = (const unsigned char*)d_in[1];
  const unsigned char* melm = (const unsigned char*)d_in[2];
  const float* pitch_truth  = (const float*)d_in[3];
  const float* energy_truth = (const float*)d_in[4];
  const int*   dur          = (const int*)d_in[5];
  const float* conv1_w = (const float*)d_in[6];
  const float* conv1_b = (const float*)d_in[7];
  const float* ln1_g   = (const float*)d_in[8];
  const float* ln1_b   = (const float*)d_in[9];
  const float* conv2_w = (const float*)d_in[10];
  const float* conv2_b = (const float*)d_in[11];
  const float* ln2_g   = (const float*)d_in[12];
  const float* ln2_b   = (const float*)d_in[13];
  const float* lin_w   = (const float*)d_in[14];
  const float* lin_b   = (const float*)d_in[15];
  const float* pitch_emb   = (const float*)d_in[16];
  const float* energy_emb  = (const float*)d_in[17];
  const float* pitch_bins  = (const float*)d_in[18];
  const float* energy_bins = (const float*)d_in[19];

  float* out      = (float*)d_out;
  float* x_out    = out;                               // 32*4096*512
  float* p_pitch  = out + (size_t)B_ * T_ * D_;
  float* p_energy = p_pitch + B_ * S_;
  float* p_dur    = p_energy + B_ * S_;
  float* p_mellen = p_dur + B_ * S_;
  float* p_mask   = p_mellen + B_;

  // ws: P (16.8MB bf16 padded) | WT1 (4.7MB) | WT2 (4.7MB) | Yb (16.8MB bf16)
  //     | xa (33.6MB f32) | cum (64KB)   total ~77MB
  __hip_bfloat16* P   = (__hip_bfloat16*)d_ws;
  __hip_bfloat16* WT1 = P + (size_t)B_ * SP_ * D_;
  __hip_bfloat16* WT2 = WT1 + (size_t)3 * F_ * KK_;
  __hip_bfloat16* Yb  = WT2 + (size_t)3 * F_ * KK_;
  float* xa = (float*)(Yb + (size_t)B_ * S_ * F_);
  int*  cum = (int*)(xa + (size_t)B_ * S_ * D_);

  const dim3 blk512t(512), blk256(256), blk128(128);
  const dim3 rowGrid(B_ * S_);               // 16384
  const dim3 convGrid(512);                  // 128 M-tiles x 4 N-tiles

  zeropad_k<<<dim3(B_ * 2), blk128, 0, stream>>>(P);
  wtrans_k<<<dim3(6 * 24 * 8), blk256, 0, stream>>>(conv1_w, conv2_w, WT1, WT2);
  topad_k<<<rowGrid, blk128, 0, stream>>>(x, P);

  auto predictor = [&](int i, float* pred) {
    convmm_k<<<convGrid, blk256, 0, stream>>>(P, WT1 + (size_t)i * F_ * KK_, Yb);
    ln_pad_k<<<rowGrid, blk256, 0, stream>>>(Yb, conv1_b + (size_t)i * F_,
                                             ln1_g + (size_t)i * F_,
                                             ln1_b + (size_t)i * F_, P);
    convmm_k<<<convGrid, blk256, 0, stream>>>(P, WT2 + (size_t)i * F_ * KK_, Yb);
    lnlin_k<<<rowGrid, blk256, 0, stream>>>(Yb, conv2_b + (size_t)i * F_,
                                            ln2_g + (size_t)i * F_,
                                            ln2_b + (size_t)i * F_,
                                            lin_w + (size_t)i * F_, lin_b + i,
                                            srcm, pred);
  };

  predictor(0, p_pitch);
  addembP_k<<<rowGrid, blk128, 0, stream>>>(x, pitch_truth, pitch_bins, pitch_emb, xa, P);
  predictor(1, p_energy);
  addembP_k<<<rowGrid, blk128, 0, stream>>>(xa, energy_truth, energy_bins, energy_emb, xa, P);
  predictor(2, p_dur);

  scan_k<<<dim3(B_), blk512t, 0, stream>>>(dur, cum, p_mellen);
  gather_k<<<dim3(B_ * T_), blk128, 0, stream>>>(xa, cum, x_out);
  maskcopy_k<<<dim3((B_ * T_) / 256), blk256, 0, stream>>>(melm, p_mask);
}

// Round 5
// 427.351 us; speedup vs baseline: 1.3904x; 1.1487x over previous
//
#include <hip/hip_runtime.h>
#include <hip/hip_bf16.h>

// VarianceAdaptor: 3x (conv1d->relu->LN->conv1d->relu->LN->linear) predictors,
// embedding adds between them, then length-regulate.
// Shapes fixed: B=32, S=512, D=F=512, K=3, T=4096, NB=256.
// Round 5: conv K-loop restructured tap-major -> d-major: A rows staged once
// per d-tile (shared across 3 taps via LDS row offset), 48 MFMA per step,
// double-buffered (65KB LDS), grid=512 = 2 blocks/CU. fp32 xa dropped: addemb
// writes bf16 padded X only (single rounding); gather reads X.

#define B_ 32
#define S_ 512
#define D_ 512
#define F_ 512
#define T_ 4096
#define SP_ 514           // padded rows per batch (row0 and row513 are zeros)
#define KK_ 1536          // 3*512 contraction length

typedef __attribute__((ext_vector_type(8))) short bf16x8;
typedef __attribute__((ext_vector_type(4))) float f32x4;

__device__ __forceinline__ float bf2f(unsigned short u) {
  union { unsigned int i; float f; } c; c.i = (unsigned int)u << 16; return c.f;
}

// ---------------- zero the pad rows of X and P (once per launch) -------------
__global__ __launch_bounds__(128) void zeropad_k(__hip_bfloat16* __restrict__ X,
                                                 __hip_bfloat16* __restrict__ P) {
  const int b = blockIdx.x >> 1;
  const int r = (blockIdx.x & 1) ? (SP_ - 1) : 0;
  const size_t off = ((size_t)b * SP_ + r) * D_ + threadIdx.x * 4;
  *(ushort4*)((unsigned short*)X + off) = make_ushort4(0, 0, 0, 0);
  *(ushort4*)((unsigned short*)P + off) = make_ushort4(0, 0, 0, 0);
}

// ---------------- fp32 [B][512][512] -> bf16 padded X rows 1..512 ------------
__global__ __launch_bounds__(128) void topad_k(const float* __restrict__ in,
                                               __hip_bfloat16* __restrict__ X) {
  const int row = blockIdx.x;          // b*512 + s
  const int b = row >> 9, s = row & 511;
  const float4 v = *(const float4*)(in + (size_t)row * D_ + threadIdx.x * 4);
  __hip_bfloat16 h0 = __float2bfloat16(v.x), h1 = __float2bfloat16(v.y);
  __hip_bfloat16 h2 = __float2bfloat16(v.z), h3 = __float2bfloat16(v.w);
  ushort4 u = make_ushort4(*(unsigned short*)&h0, *(unsigned short*)&h1,
                           *(unsigned short*)&h2, *(unsigned short*)&h3);
  *(ushort4*)((unsigned short*)X + ((size_t)b * SP_ + s + 1) * D_ + threadIdx.x * 4) = u;
}

// ---------------- W [1536][512] fp32 -> WT [512][1536] bf16 (6 matrices) -----
__global__ __launch_bounds__(256) void wtrans_k(const float* __restrict__ W1,
                                                const float* __restrict__ W2,
                                                __hip_bfloat16* __restrict__ WT1,
                                                __hip_bfloat16* __restrict__ WT2) {
  __shared__ float tb[64][65];
  const int bid = blockIdx.x;          // w*192 + kt*8 + ft
  const int w = bid / 192;
  const int kt = (bid % 192) >> 3;     // 24 kk-tiles of 64
  const int ft = bid & 7;              // 8 f-tiles of 64
  const float* src = (w < 3) ? (W1 + (size_t)w * KK_ * F_)
                             : (W2 + (size_t)(w - 3) * KK_ * F_);
  __hip_bfloat16* dst = (w < 3) ? (WT1 + (size_t)w * KK_ * F_)
                                : (WT2 + (size_t)(w - 3) * KK_ * F_);
  const int ty = threadIdx.x >> 4, tx = threadIdx.x & 15;
  #pragma unroll
  for (int j = 0; j < 4; ++j) {
    const int r = ty + j * 16;         // kk within tile
    const float4 v = *(const float4*)(src + (size_t)(kt * 64 + r) * F_ + ft * 64 + tx * 4);
    tb[r][tx * 4 + 0] = v.x; tb[r][tx * 4 + 1] = v.y;
    tb[r][tx * 4 + 2] = v.z; tb[r][tx * 4 + 3] = v.w;
  }
  __syncthreads();
  #pragma unroll
  for (int j = 0; j < 4; ++j) {
    const int r = ty + j * 16;         // f within tile
    __hip_bfloat16 h0 = __float2bfloat16(tb[tx * 4 + 0][r]);
    __hip_bfloat16 h1 = __float2bfloat16(tb[tx * 4 + 1][r]);
    __hip_bfloat16 h2 = __float2bfloat16(tb[tx * 4 + 2][r]);
    __hip_bfloat16 h3 = __float2bfloat16(tb[tx * 4 + 3][r]);
    ushort4 u = make_ushort4(*(unsigned short*)&h0, *(unsigned short*)&h1,
                             *(unsigned short*)&h2, *(unsigned short*)&h3);
    *(ushort4*)((unsigned short*)dst + (size_t)(ft * 64 + r) * KK_ + kt * 64 + tx * 4) = u;
  }
}

// ---------------- conv as bf16 MFMA GEMM, d-major K-loop, dbuf ---------------
// Y[b*512+st+i][f0+j] = sum_{tap,d} Pin[b][st+i+tap][d] * WT[f0+j][tap*512+d]
// Per d-step: A rows st..st+129 (130x32) staged once, shared by 3 taps.
__global__ __launch_bounds__(256) void convmm_k(const __hip_bfloat16* __restrict__ Pin,
                                                const __hip_bfloat16* __restrict__ WT,
                                                __hip_bfloat16* __restrict__ Yb) {
  __shared__ __align__(16) __hip_bfloat16 As[2][4224];   // 132 rows x 64B, 8.25KB x2
  __shared__ __align__(16) __hip_bfloat16 Bs[2][12288];  // [3][128][32], 24KB x2
  const int nt = blockIdx.x & 3;       // 4 N-tiles (f)
  const int mt = blockIdx.x >> 2;      // 128 M-tiles (rows)
  const int b  = mt >> 2;              // 4 M-tiles per batch
  const int st = (mt & 3) * 128;
  const int f0 = nt * 128;
  const int t = threadIdx.x;
  const int lane = t & 63;
  const int wave = t >> 6;
  const int wm = (wave >> 1) * 64;     // 2x2 wave grid, 64x64 each
  const int wn = (wave & 1) * 64;

  f32x4 acc[4][4];
  #pragma unroll
  for (int m = 0; m < 4; ++m)
    #pragma unroll
    for (int n = 0; n < 4; ++n) acc[m][n] = (f32x4){0.f, 0.f, 0.f, 0.f};

  const __hip_bfloat16* Xb = Pin + (size_t)b * SP_ * D_;

  auto stage = [&](int dstep, int buf) {
    const int d0 = dstep * 32;
    // A: 520 chunks of 16B = rows st..st+129 x 32 d-elems
    int c = t;
    #pragma unroll
    for (int i = 0; i < 3; ++i, c += 256) {
      if (c < 520) {
        const __hip_bfloat16* ga = Xb + (size_t)(st + (c >> 2)) * D_ + d0 + (c & 3) * 8;
        __builtin_amdgcn_global_load_lds(
            (const __attribute__((address_space(1))) void*)ga,
            (__attribute__((address_space(3))) void*)((char*)&As[buf][0] + c * 16),
            16, 0, 0);
      }
    }
    // B: 1536 chunks = [tap][128 f][4 ch]
    c = t;
    #pragma unroll
    for (int i = 0; i < 6; ++i, c += 256) {
      const int tap = c >> 9, rem = c & 511, fr = rem >> 2, ch = rem & 3;
      const __hip_bfloat16* gb = WT + (size_t)(f0 + fr) * KK_ + tap * 512 + d0 + ch * 8;
      __builtin_amdgcn_global_load_lds(
          (const __attribute__((address_space(1))) void*)gb,
          (__attribute__((address_space(3))) void*)((char*)&Bs[buf][0] + c * 16),
          16, 0, 0);
    }
  };

  stage(0, 0);
  __syncthreads();
  const int rA = lane & 15;
  const int kc = (lane >> 4) * 16;     // 16B k-chunk within 64B row
  for (int dstep = 0; dstep < 16; ++dstep) {
    const int cur = dstep & 1;
    if (dstep < 15) stage(dstep + 1, cur ^ 1);   // prefetch overlaps MFMA below
    const char* Ab = (const char*)&As[cur][0];
    const char* Bb = (const char*)&Bs[cur][0];
    #pragma unroll
    for (int tap = 0; tap < 3; ++tap) {
      bf16x8 af[4], bfr[4];
      #pragma unroll
      for (int m = 0; m < 4; ++m)
        af[m] = *(const bf16x8*)(Ab + (tap + wm + m * 16 + rA) * 64 + kc);
      #pragma unroll
      for (int n = 0; n < 4; ++n)
        bfr[n] = *(const bf16x8*)(Bb + tap * 8192 + (wn + n * 16 + rA) * 64 + kc);
      #pragma unroll
      for (int m = 0; m < 4; ++m)
        #pragma unroll
        for (int n = 0; n < 4; ++n)
          acc[m][n] = __builtin_amdgcn_mfma_f32_16x16x32_bf16(af[m], bfr[n], acc[m][n], 0, 0, 0);
    }
    __syncthreads();                   // drains prefetch; guards buf reuse
  }
  // C/D layout: col = lane&15, row = (lane>>4)*4 + reg   [m89-verified]
  const int col = lane & 15;
  const int r0 = (lane >> 4) * 4;
  unsigned short* Yu = (unsigned short*)Yb;
  #pragma unroll
  for (int m = 0; m < 4; ++m) {
    #pragma unroll
    for (int n = 0; n < 4; ++n) {
      unsigned short* yp =
          Yu + ((size_t)b * S_ + st + wm + m * 16 + r0) * F_ + f0 + wn + n * 16 + col;
      #pragma unroll
      for (int r = 0; r < 4; ++r) {
        __hip_bfloat16 h = __float2bfloat16(acc[m][n][r]);
        yp[(size_t)r * F_] = *(unsigned short*)&h;
      }
    }
  }
}

// ------------- bias + relu + layernorm; bf16 in, bf16-padded out (into P) ----
__global__ __launch_bounds__(256) void ln_pad_k(const __hip_bfloat16* __restrict__ Yb,
                                                const float* __restrict__ bias,
                                                const float* __restrict__ g,
                                                const float* __restrict__ be,
                                                __hip_bfloat16* __restrict__ P) {
  const int row = blockIdx.x;          // b*512 + s
  const int t   = threadIdx.x;
  const ushort2 u2 = *(const ushort2*)((const unsigned short*)Yb + (size_t)row * F_ + t * 2);
  float2 v = make_float2(bf2f(u2.x), bf2f(u2.y));
  v.x = fmaxf(v.x + bias[t * 2], 0.f);
  v.y = fmaxf(v.y + bias[t * 2 + 1], 0.f);
  __shared__ float red[6];
  float s = v.x + v.y;
  #pragma unroll
  for (int o = 32; o > 0; o >>= 1) s += __shfl_down(s, o, 64);
  const int lane = t & 63, w = t >> 6;
  if (lane == 0) red[w] = s;
  __syncthreads();
  if (t == 0) red[4] = red[0] + red[1] + red[2] + red[3];
  __syncthreads();
  const float mean = red[4] * (1.f / F_);
  const float dx = v.x - mean, dy = v.y - mean;
  float q = dx * dx + dy * dy;
  #pragma unroll
  for (int o = 32; o > 0; o >>= 1) q += __shfl_down(q, o, 64);
  __syncthreads();
  if (lane == 0) red[w] = q;
  __syncthreads();
  if (t == 0) red[5] = red[0] + red[1] + red[2] + red[3];
  __syncthreads();
  const float inv = rsqrtf(red[5] * (1.f / F_) + 1e-5f);
  __hip_bfloat16 h0 = __float2bfloat16(dx * inv * g[t * 2]     + be[t * 2]);
  __hip_bfloat16 h1 = __float2bfloat16(dy * inv * g[t * 2 + 1] + be[t * 2 + 1]);
  ushort2 u = make_ushort2(*(unsigned short*)&h0, *(unsigned short*)&h1);
  const int b = row >> 9, sr = row & 511;
  *(ushort2*)((unsigned short*)P + ((size_t)b * SP_ + sr + 1) * D_ + t * 2) = u;
}

// ------------- bias + relu + LN + fused linear head: pred only ---------------
__global__ __launch_bounds__(256) void lnlin_k(const __hip_bfloat16* __restrict__ Yb,
                                               const float* __restrict__ bias,
                                               const float* __restrict__ g,
                                               const float* __restrict__ be,
                                               const float* __restrict__ wl,
                                               const float* __restrict__ bl,
                                               const unsigned char* __restrict__ mask,
                                               float* __restrict__ pred) {
  const int row = blockIdx.x;
  const int t   = threadIdx.x;
  const ushort2 u2 = *(const ushort2*)((const unsigned short*)Yb + (size_t)row * F_ + t * 2);
  float2 v = make_float2(bf2f(u2.x), bf2f(u2.y));
  v.x = fmaxf(v.x + bias[t * 2], 0.f);
  v.y = fmaxf(v.y + bias[t * 2 + 1], 0.f);
  __shared__ float red[6];
  float s = v.x + v.y;
  #pragma unroll
  for (int o = 32; o > 0; o >>= 1) s += __shfl_down(s, o, 64);
  const int lane = t & 63, w = t >> 6;
  if (lane == 0) red[w] = s;
  __syncthreads();
  if (t == 0) red[4] = red[0] + red[1] + red[2] + red[3];
  __syncthreads();
  const float mean = red[4] * (1.f / F_);
  const float dx = v.x - mean, dy = v.y - mean;
  float q = dx * dx + dy * dy;
  #pragma unroll
  for (int o = 32; o > 0; o >>= 1) q += __shfl_down(q, o, 64);
  __syncthreads();
  if (lane == 0) red[w] = q;
  __syncthreads();
  if (t == 0) red[5] = red[0] + red[1] + red[2] + red[3];
  __syncthreads();
  const float inv = rsqrtf(red[5] * (1.f / F_) + 1e-5f);
  const float ox = dx * inv * g[t * 2]     + be[t * 2];
  const float oy = dy * inv * g[t * 2 + 1] + be[t * 2 + 1];
  float dp = ox * wl[t * 2] + oy * wl[t * 2 + 1];
  #pragma unroll
  for (int o = 32; o > 0; o >>= 1) dp += __shfl_down(dp, o, 64);
  if (lane == 0) red[w] = dp;
  __syncthreads();
  if (t == 0)
    pred[row] = mask[row] ? 0.f : (red[0] + red[1] + red[2] + red[3] + bl[0]);
}

// ----- X[padded row] = bf16(x + emb1[idx1] (+ emb2[idx2]))  ------------------
__global__ __launch_bounds__(128) void addemb_k(const float* __restrict__ x,
                                                const float* __restrict__ truth1,
                                                const float* __restrict__ bins1,
                                                const float* __restrict__ emb1,
                                                const float* __restrict__ truth2,
                                                const float* __restrict__ bins2,
                                                const float* __restrict__ emb2,
                                                __hip_bfloat16* __restrict__ X) {
  const int row = blockIdx.x;  // b*S + s
  __shared__ int sidx1, sidx2;
  if (threadIdx.x == 0) {
    float v = truth1[row];
    int lo = 0, hi = 255;  // NB-1 bins
    while (lo < hi) { const int mid = (lo + hi) >> 1; if (bins1[mid] < v) lo = mid + 1; else hi = mid; }
    sidx1 = lo;            // searchsorted side='left'
    if (truth2) {
      v = truth2[row]; lo = 0; hi = 255;
      while (lo < hi) { const int mid = (lo + hi) >> 1; if (bins2[mid] < v) lo = mid + 1; else hi = mid; }
      sidx2 = lo;
    }
  }
  __syncthreads();
  float4 a = *(const float4*)(x + (size_t)row * D_ + threadIdx.x * 4);
  const float4 e1 = *(const float4*)(emb1 + (size_t)sidx1 * D_ + threadIdx.x * 4);
  a.x += e1.x; a.y += e1.y; a.z += e1.z; a.w += e1.w;
  if (truth2) {
    const float4 e2 = *(const float4*)(emb2 + (size_t)sidx2 * D_ + threadIdx.x * 4);
    a.x += e2.x; a.y += e2.y; a.z += e2.z; a.w += e2.w;
  }
  __hip_bfloat16 h0 = __float2bfloat16(a.x), h1 = __float2bfloat16(a.y);
  __hip_bfloat16 h2 = __float2bfloat16(a.z), h3 = __float2bfloat16(a.w);
  ushort4 u = make_ushort4(*(unsigned short*)&h0, *(unsigned short*)&h1,
                           *(unsigned short*)&h2, *(unsigned short*)&h3);
  const int b = row >> 9, s = row & 511;
  *(ushort4*)((unsigned short*)X + ((size_t)b * SP_ + s + 1) * D_ + threadIdx.x * 4) = u;
}

// ------------- inclusive cumsum of durations per batch; mel_len as float -----
__global__ __launch_bounds__(512) void scan_k(const int* __restrict__ dur,
                                              int* __restrict__ cum,
                                              float* __restrict__ mel_len) {
  __shared__ int sh[S_];
  const int b = blockIdx.x, t = threadIdx.x;
  sh[t] = dur[b * S_ + t];
  __syncthreads();
  for (int off = 1; off < S_; off <<= 1) {
    const int add = (t >= off) ? sh[t - off] : 0;
    __syncthreads();
    sh[t] += add;
    __syncthreads();
  }
  cum[b * S_ + t] = sh[t];
  if (t == S_ - 1) mel_len[b] = (float)sh[t];
}

// ------------- length regulate: out[b,pos,:] = valid ? X[b,idx,:] : 0 --------
__global__ __launch_bounds__(128) void gather_k(const __hip_bfloat16* __restrict__ X,
                                                const int* __restrict__ cum,
                                                float* __restrict__ out) {
  const int b   = blockIdx.x >> 12;    // T=4096 positions per batch
  const int pos = blockIdx.x & (T_ - 1);
  __shared__ int sidx, svalid;
  if (threadIdx.x == 0) {
    const int* c = cum + b * S_;
    int lo = 0, hi = S_;
    while (lo < hi) {                  // upper_bound: first c[i] > pos
      const int mid = (lo + hi) >> 1;
      if (c[mid] <= pos) lo = mid + 1; else hi = mid;
    }
    sidx = (lo < S_ - 1) ? lo : (S_ - 1);
    svalid = (pos < c[S_ - 1]) ? 1 : 0;
  }
  __syncthreads();
  float4 v = make_float4(0.f, 0.f, 0.f, 0.f);
  if (svalid) {
    const ushort4 u = *(const ushort4*)((const unsigned short*)X +
                        ((size_t)b * SP_ + sidx + 1) * D_ + threadIdx.x * 4);
    v = make_float4(bf2f(u.x), bf2f(u.y), bf2f(u.z), bf2f(u.w));
  }
  *(float4*)(out + ((size_t)b * T_ + pos) * D_ + threadIdx.x * 4) = v;
}

// ------------- mel_mask bool -> float ---------------------------------------
__global__ __launch_bounds__(256) void maskcopy_k(const unsigned char* __restrict__ m,
                                                  float* __restrict__ out) {
  const int i = blockIdx.x * 256 + threadIdx.x;
  out[i] = m[i] ? 1.f : 0.f;
}

extern "C" void kernel_launch(void* const* d_in, const int* in_sizes, int n_in,
                              void* d_out, int out_size, void* d_ws, size_t ws_size,
                              hipStream_t stream) {
  const float* x            = (const float*)d_in[0];
  const unsigned char* srcm = (const unsigned char*)d_in[1];
  const unsigned char* melm = (const unsigned char*)d_in[2];
  const float* pitch_truth  = (const float*)d_in[3];
  const float* energy_truth = (const float*)d_in[4];
  const int*   dur          = (const int*)d_in[5];
  const float* conv1_w = (const float*)d_in[6];
  const float* conv1_b = (const float*)d_in[7];
  const float* ln1_g   = (const float*)d_in[8];
  const float* ln1_b   = (const float*)d_in[9];
  const float* conv2_w = (const float*)d_in[10];
  const float* conv2_b = (const float*)d_in[11];
  const float* ln2_g   = (const float*)d_in[12];
  const float* ln2_b   = (const float*)d_in[13];
  const float* lin_w   = (const float*)d_in[14];
  const float* lin_b   = (const float*)d_in[15];
  const float* pitch_emb   = (const float*)d_in[16];
  const float* energy_emb  = (const float*)d_in[17];
  const float* pitch_bins  = (const float*)d_in[18];
  const float* energy_bins = (const float*)d_in[19];

  float* out      = (float*)d_out;
  float* x_out    = out;                               // 32*4096*512
  float* p_pitch  = out + (size_t)B_ * T_ * D_;
  float* p_energy = p_pitch + B_ * S_;
  float* p_dur    = p_energy + B_ * S_;
  float* p_mellen = p_dur + B_ * S_;
  float* p_mask   = p_mellen + B_;

  // ws: X (16.9MB) | P (16.9MB) | WT1 (4.7MB) | WT2 (4.7MB) | Yb (16.8MB)
  //     | cum (64KB)   total ~60MB
  __hip_bfloat16* X   = (__hip_bfloat16*)d_ws;
  __hip_bfloat16* P   = X + (size_t)B_ * SP_ * D_;
  __hip_bfloat16* WT1 = P + (size_t)B_ * SP_ * D_;
  __hip_bfloat16* WT2 = WT1 + (size_t)3 * F_ * KK_;
  __hip_bfloat16* Yb  = WT2 + (size_t)3 * F_ * KK_;
  int*  cum = (int*)(Yb + (size_t)B_ * S_ * F_);

  const dim3 blk512t(512), blk256(256), blk128(128);
  const dim3 rowGrid(B_ * S_);               // 16384
  const dim3 convGrid(512);                  // 128 M-tiles x 4 N-tiles

  zeropad_k<<<dim3(B_ * 2), blk128, 0, stream>>>(X, P);
  wtrans_k<<<dim3(6 * 24 * 8), blk256, 0, stream>>>(conv1_w, conv2_w, WT1, WT2);
  topad_k<<<rowGrid, blk128, 0, stream>>>(x, X);

  auto predictor = [&](int i, float* pred) {
    convmm_k<<<convGrid, blk256, 0, stream>>>(X, WT1 + (size_t)i * F_ * KK_, Yb);
    ln_pad_k<<<rowGrid, blk256, 0, stream>>>(Yb, conv1_b + (size_t)i * F_,
                                             ln1_g + (size_t)i * F_,
                                             ln1_b + (size_t)i * F_, P);
    convmm_k<<<convGrid, blk256, 0, stream>>>(P, WT2 + (size_t)i * F_ * KK_, Yb);
    lnlin_k<<<rowGrid, blk256, 0, stream>>>(Yb, conv2_b + (size_t)i * F_,
                                            ln2_g + (size_t)i * F_,
                                            ln2_b + (size_t)i * F_,
                                            lin_w + (size_t)i * F_, lin_b + i,
                                            srcm, pred);
  };

  predictor(0, p_pitch);
  addemb_k<<<rowGrid, blk128, 0, stream>>>(x, pitch_truth, pitch_bins, pitch_emb,
                                           nullptr, nullptr, nullptr, X);
  predictor(1, p_energy);
  addemb_k<<<rowGrid, blk128, 0, stream>>>(x, pitch_truth, pitch_bins, pitch_emb,
                                           energy_truth, energy_bins, energy_emb, X);
  predictor(2, p_dur);

  scan_k<<<dim3(B_), blk512t, 0, stream>>>(dur, cum, p_mellen);
  gather_k<<<dim3(B_ * T_), blk128, 0, stream>>>(X, cum, x_out);
  maskcopy_k<<<dim3((B_ * T_) / 256), blk256, 0, stream>>>(melm, p_mask);
}

// Round 6
// 424.268 us; speedup vs baseline: 1.4005x; 1.0073x over previous
//
#include <hip/hip_runtime.h>
#include <hip/hip_bf16.h>

// VarianceAdaptor: 3x (conv1d->relu->LN->conv1d->relu->LN->linear) predictors,
// embedding adds between them, then length-regulate.
// Shapes fixed: B=32, S=512, D=F=512, K=3, T=4096, NB=256.
// Round 6: conv K-loop -> counted-vmcnt pipeline (T4): uniform 9 loads/stage,
// s_waitcnt vmcnt(9) + raw s_barrier pairs, no vmcnt(0) drain in loop.
// + XCD-aware block swizzle (T1). Rest identical to R5.

#define B_ 32
#define S_ 512
#define D_ 512
#define F_ 512
#define T_ 4096
#define SP_ 514           // padded rows per batch (row0 and row513 are zeros)
#define KK_ 1536          // 3*512 contraction length

typedef __attribute__((ext_vector_type(8))) short bf16x8;
typedef __attribute__((ext_vector_type(4))) float f32x4;

__device__ __forceinline__ float bf2f(unsigned short u) {
  union { unsigned int i; float f; } c; c.i = (unsigned int)u << 16; return c.f;
}

// ---------------- zero the pad rows of X and P (once per launch) -------------
__global__ __launch_bounds__(128) void zeropad_k(__hip_bfloat16* __restrict__ X,
                                                 __hip_bfloat16* __restrict__ P) {
  const int b = blockIdx.x >> 1;
  const int r = (blockIdx.x & 1) ? (SP_ - 1) : 0;
  const size_t off = ((size_t)b * SP_ + r) * D_ + threadIdx.x * 4;
  *(ushort4*)((unsigned short*)X + off) = make_ushort4(0, 0, 0, 0);
  *(ushort4*)((unsigned short*)P + off) = make_ushort4(0, 0, 0, 0);
}

// ---------------- fp32 [B][512][512] -> bf16 padded X rows 1..512 ------------
__global__ __launch_bounds__(128) void topad_k(const float* __restrict__ in,
                                               __hip_bfloat16* __restrict__ X) {
  const int row = blockIdx.x;          // b*512 + s
  const int b = row >> 9, s = row & 511;
  const float4 v = *(const float4*)(in + (size_t)row * D_ + threadIdx.x * 4);
  __hip_bfloat16 h0 = __float2bfloat16(v.x), h1 = __float2bfloat16(v.y);
  __hip_bfloat16 h2 = __float2bfloat16(v.z), h3 = __float2bfloat16(v.w);
  ushort4 u = make_ushort4(*(unsigned short*)&h0, *(unsigned short*)&h1,
                           *(unsigned short*)&h2, *(unsigned short*)&h3);
  *(ushort4*)((unsigned short*)X + ((size_t)b * SP_ + s + 1) * D_ + threadIdx.x * 4) = u;
}

// ---------------- W [1536][512] fp32 -> WT [512][1536] bf16 (6 matrices) -----
__global__ __launch_bounds__(256) void wtrans_k(const float* __restrict__ W1,
                                                const float* __restrict__ W2,
                                                __hip_bfloat16* __restrict__ WT1,
                                                __hip_bfloat16* __restrict__ WT2) {
  __shared__ float tb[64][65];
  const int bid = blockIdx.x;          // w*192 + kt*8 + ft
  const int w = bid / 192;
  const int kt = (bid % 192) >> 3;     // 24 kk-tiles of 64
  const int ft = bid & 7;              // 8 f-tiles of 64
  const float* src = (w < 3) ? (W1 + (size_t)w * KK_ * F_)
                             : (W2 + (size_t)(w - 3) * KK_ * F_);
  __hip_bfloat16* dst = (w < 3) ? (WT1 + (size_t)w * KK_ * F_)
                                : (WT2 + (size_t)(w - 3) * KK_ * F_);
  const int ty = threadIdx.x >> 4, tx = threadIdx.x & 15;
  #pragma unroll
  for (int j = 0; j < 4; ++j) {
    const int r = ty + j * 16;         // kk within tile
    const float4 v = *(const float4*)(src + (size_t)(kt * 64 + r) * F_ + ft * 64 + tx * 4);
    tb[r][tx * 4 + 0] = v.x; tb[r][tx * 4 + 1] = v.y;
    tb[r][tx * 4 + 2] = v.z; tb[r][tx * 4 + 3] = v.w;
  }
  __syncthreads();
  #pragma unroll
  for (int j = 0; j < 4; ++j) {
    const int r = ty + j * 16;         // f within tile
    __hip_bfloat16 h0 = __float2bfloat16(tb[tx * 4 + 0][r]);
    __hip_bfloat16 h1 = __float2bfloat16(tb[tx * 4 + 1][r]);
    __hip_bfloat16 h2 = __float2bfloat16(tb[tx * 4 + 2][r]);
    __hip_bfloat16 h3 = __float2bfloat16(tb[tx * 4 + 3][r]);
    ushort4 u = make_ushort4(*(unsigned short*)&h0, *(unsigned short*)&h1,
                             *(unsigned short*)&h2, *(unsigned short*)&h3);
    *(ushort4*)((unsigned short*)dst + (size_t)(ft * 64 + r) * KK_ + kt * 64 + tx * 4) = u;
  }
}

// ---------------- conv as bf16 MFMA GEMM, d-major, counted-vmcnt pipeline ----
// Y[b*512+st+i][f0+j] = sum_{tap,d} Pin[b][st+i+tap][d] * WT[f0+j][tap*512+d]
__global__ __launch_bounds__(256) void convmm_k(const __hip_bfloat16* __restrict__ Pin,
                                                const __hip_bfloat16* __restrict__ WT,
                                                __hip_bfloat16* __restrict__ Yb) {
  __shared__ __align__(16) __hip_bfloat16 As[2][4224];   // 130 rows x 64B used
  __shared__ __align__(16) __hip_bfloat16 Bs[2][12288];  // [3][128][32]
  // T1: XCD swizzle (512 blocks, 8 XCDs -> 64 contiguous per XCD).
  // Groups the 4 N-tiles of each M-tile on one XCD (shared A + W in L2).
  const int swz = (blockIdx.x & 7) * 64 + (blockIdx.x >> 3);
  const int nt = swz & 3;              // 4 N-tiles (f)
  const int mt = swz >> 2;             // 128 M-tiles (rows)
  const int b  = mt >> 2;              // 4 M-tiles per batch
  const int st = (mt & 3) * 128;
  const int f0 = nt * 128;
  const int t = threadIdx.x;
  const int lane = t & 63;
  const int wave = t >> 6;
  const int wm = (wave >> 1) * 64;     // 2x2 wave grid, 64x64 each
  const int wn = (wave & 1) * 64;

  f32x4 acc[4][4];
  #pragma unroll
  for (int m = 0; m < 4; ++m)
    #pragma unroll
    for (int n = 0; n < 4; ++n) acc[m][n] = (f32x4){0.f, 0.f, 0.f, 0.f};

  const __hip_bfloat16* Xb = Pin + (size_t)b * SP_ * D_;

  // Every thread issues EXACTLY 9 global_load_lds per stage (vmcnt-uniform):
  // A: 520 chunks over 256 threads x 3 (dups for c>=520 re-write chunk c-520
  // with identical data); B: 1536 chunks = 6/thread exact.
  auto stage = [&](int dstep, int buf) {
    const int d0 = dstep * 32;
    #pragma unroll
    for (int i = 0; i < 3; ++i) {
      int c = t + i * 256;
      c = (c < 520) ? c : (c - 520);   // benign duplicate write, keeps count uniform
      const __hip_bfloat16* ga = Xb + (size_t)(st + (c >> 2)) * D_ + d0 + (c & 3) * 8;
      __builtin_amdgcn_global_load_lds(
          (const __attribute__((address_space(1))) void*)ga,
          (__attribute__((address_space(3))) void*)((char*)&As[buf][0] + c * 16),
          16, 0, 0);
    }
    #pragma unroll
    for (int i = 0; i < 6; ++i) {
      const int c = t + i * 256;
      const int tap = c >> 9, rem = c & 511, fr = rem >> 2, ch = rem & 3;
      const __hip_bfloat16* gb = WT + (size_t)(f0 + fr) * KK_ + tap * 512 + d0 + ch * 8;
      __builtin_amdgcn_global_load_lds(
          (const __attribute__((address_space(1))) void*)gb,
          (__attribute__((address_space(3))) void*)((char*)&Bs[buf][0] + c * 16),
          16, 0, 0);
    }
  };

  stage(0, 0);
  const int rA = lane & 15;
  const int kc = (lane >> 4) * 16;     // 16B k-chunk within 64B row
  for (int dstep = 0; dstep < 16; ++dstep) {
    const int cur = dstep & 1;
    if (dstep < 15) {
      stage(dstep + 1, cur ^ 1);       // new 9 loads stay in flight across barrier
      asm volatile("s_waitcnt vmcnt(9)" ::: "memory");  // old stage retired
    } else {
      asm volatile("s_waitcnt vmcnt(0)" ::: "memory");
    }
    __builtin_amdgcn_s_barrier();      // publish: all waves' stage(dstep) done
    __builtin_amdgcn_sched_barrier(0);
    const char* Ab = (const char*)&As[cur][0];
    const char* Bb = (const char*)&Bs[cur][0];
    #pragma unroll
    for (int tap = 0; tap < 3; ++tap) {
      bf16x8 af[4], bfr[4];
      #pragma unroll
      for (int m = 0; m < 4; ++m)
        af[m] = *(const bf16x8*)(Ab + (tap + wm + m * 16 + rA) * 64 + kc);
      #pragma unroll
      for (int n = 0; n < 4; ++n)
        bfr[n] = *(const bf16x8*)(Bb + tap * 8192 + (wn + n * 16 + rA) * 64 + kc);
      #pragma unroll
      for (int m = 0; m < 4; ++m)
        #pragma unroll
        for (int n = 0; n < 4; ++n)
          acc[m][n] = __builtin_amdgcn_mfma_f32_16x16x32_bf16(af[m], bfr[n], acc[m][n], 0, 0, 0);
    }
    __builtin_amdgcn_sched_barrier(0);
    __builtin_amdgcn_s_barrier();      // all waves done reading buf cur
  }
  // C/D layout: col = lane&15, row = (lane>>4)*4 + reg   [m89-verified]
  const int col = lane & 15;
  const int r0 = (lane >> 4) * 4;
  unsigned short* Yu = (unsigned short*)Yb;
  #pragma unroll
  for (int m = 0; m < 4; ++m) {
    #pragma unroll
    for (int n = 0; n < 4; ++n) {
      unsigned short* yp =
          Yu + ((size_t)b * S_ + st + wm + m * 16 + r0) * F_ + f0 + wn + n * 16 + col;
      #pragma unroll
      for (int r = 0; r < 4; ++r) {
        __hip_bfloat16 h = __float2bfloat16(acc[m][n][r]);
        yp[(size_t)r * F_] = *(unsigned short*)&h;
      }
    }
  }
}

// ------------- bias + relu + layernorm; bf16 in, bf16-padded out (into P) ----
__global__ __launch_bounds__(256) void ln_pad_k(const __hip_bfloat16* __restrict__ Yb,
                                                const float* __restrict__ bias,
                                                const float* __restrict__ g,
                                                const float* __restrict__ be,
                                                __hip_bfloat16* __restrict__ P) {
  const int row = blockIdx.x;          // b*512 + s
  const int t   = threadIdx.x;
  const ushort2 u2 = *(const ushort2*)((const unsigned short*)Yb + (size_t)row * F_ + t * 2);
  float2 v = make_float2(bf2f(u2.x), bf2f(u2.y));
  v.x = fmaxf(v.x + bias[t * 2], 0.f);
  v.y = fmaxf(v.y + bias[t * 2 + 1], 0.f);
  __shared__ float red[6];
  float s = v.x + v.y;
  #pragma unroll
  for (int o = 32; o > 0; o >>= 1) s += __shfl_down(s, o, 64);
  const int lane = t & 63, w = t >> 6;
  if (lane == 0) red[w] = s;
  __syncthreads();
  if (t == 0) red[4] = red[0] + red[1] + red[2] + red[3];
  __syncthreads();
  const float mean = red[4] * (1.f / F_);
  const float dx = v.x - mean, dy = v.y - mean;
  float q = dx * dx + dy * dy;
  #pragma unroll
  for (int o = 32; o > 0; o >>= 1) q += __shfl_down(q, o, 64);
  __syncthreads();
  if (lane == 0) red[w] = q;
  __syncthreads();
  if (t == 0) red[5] = red[0] + red[1] + red[2] + red[3];
  __syncthreads();
  const float inv = rsqrtf(red[5] * (1.f / F_) + 1e-5f);
  __hip_bfloat16 h0 = __float2bfloat16(dx * inv * g[t * 2]     + be[t * 2]);
  __hip_bfloat16 h1 = __float2bfloat16(dy * inv * g[t * 2 + 1] + be[t * 2 + 1]);
  ushort2 u = make_ushort2(*(unsigned short*)&h0, *(unsigned short*)&h1);
  const int b = row >> 9, sr = row & 511;
  *(ushort2*)((unsigned short*)P + ((size_t)b * SP_ + sr + 1) * D_ + t * 2) = u;
}

// ------------- bias + relu + LN + fused linear head: pred only ---------------
__global__ __launch_bounds__(256) void lnlin_k(const __hip_bfloat16* __restrict__ Yb,
                                               const float* __restrict__ bias,
                                               const float* __restrict__ g,
                                               const float* __restrict__ be,
                                               const float* __restrict__ wl,
                                               const float* __restrict__ bl,
                                               const unsigned char* __restrict__ mask,
                                               float* __restrict__ pred) {
  const int row = blockIdx.x;
  const int t   = threadIdx.x;
  const ushort2 u2 = *(const ushort2*)((const unsigned short*)Yb + (size_t)row * F_ + t * 2);
  float2 v = make_float2(bf2f(u2.x), bf2f(u2.y));
  v.x = fmaxf(v.x + bias[t * 2], 0.f);
  v.y = fmaxf(v.y + bias[t * 2 + 1], 0.f);
  __shared__ float red[6];
  float s = v.x + v.y;
  #pragma unroll
  for (int o = 32; o > 0; o >>= 1) s += __shfl_down(s, o, 64);
  const int lane = t & 63, w = t >> 6;
  if (lane == 0) red[w] = s;
  __syncthreads();
  if (t == 0) red[4] = red[0] + red[1] + red[2] + red[3];
  __syncthreads();
  const float mean = red[4] * (1.f / F_);
  const float dx = v.x - mean, dy = v.y - mean;
  float q = dx * dx + dy * dy;
  #pragma unroll
  for (int o = 32; o > 0; o >>= 1) q += __shfl_down(q, o, 64);
  __syncthreads();
  if (lane == 0) red[w] = q;
  __syncthreads();
  if (t == 0) red[5] = red[0] + red[1] + red[2] + red[3];
  __syncthreads();
  const float inv = rsqrtf(red[5] * (1.f / F_) + 1e-5f);
  const float ox = dx * inv * g[t * 2]     + be[t * 2];
  const float oy = dy * inv * g[t * 2 + 1] + be[t * 2 + 1];
  float dp = ox * wl[t * 2] + oy * wl[t * 2 + 1];
  #pragma unroll
  for (int o = 32; o > 0; o >>= 1) dp += __shfl_down(dp, o, 64);
  if (lane == 0) red[w] = dp;
  __syncthreads();
  if (t == 0)
    pred[row] = mask[row] ? 0.f : (red[0] + red[1] + red[2] + red[3] + bl[0]);
}

// ----- X[padded row] = bf16(x + emb1[idx1] (+ emb2[idx2]))  ------------------
__global__ __launch_bounds__(128) void addemb_k(const float* __restrict__ x,
                                                const float* __restrict__ truth1,
                                                const float* __restrict__ bins1,
                                                const float* __restrict__ emb1,
                                                const float* __restrict__ truth2,
                                                const float* __restrict__ bins2,
                                                const float* __restrict__ emb2,
                                                __hip_bfloat16* __restrict__ X) {
  const int row = blockIdx.x;  // b*S + s
  __shared__ int sidx1, sidx2;
  if (threadIdx.x == 0) {
    float v = truth1[row];
    int lo = 0, hi = 255;  // NB-1 bins
    while (lo < hi) { const int mid = (lo + hi) >> 1; if (bins1[mid] < v) lo = mid + 1; else hi = mid; }
    sidx1 = lo;            // searchsorted side='left'
    if (truth2) {
      v = truth2[row]; lo = 0; hi = 255;
      while (lo < hi) { const int mid = (lo + hi) >> 1; if (bins2[mid] < v) lo = mid + 1; else hi = mid; }
      sidx2 = lo;
    }
  }
  __syncthreads();
  float4 a = *(const float4*)(x + (size_t)row * D_ + threadIdx.x * 4);
  const float4 e1 = *(const float4*)(emb1 + (size_t)sidx1 * D_ + threadIdx.x * 4);
  a.x += e1.x; a.y += e1.y; a.z += e1.z; a.w += e1.w;
  if (truth2) {
    const float4 e2 = *(const float4*)(emb2 + (size_t)sidx2 * D_ + threadIdx.x * 4);
    a.x += e2.x; a.y += e2.y; a.z += e2.z; a.w += e2.w;
  }
  __hip_bfloat16 h0 = __float2bfloat16(a.x), h1 = __float2bfloat16(a.y);
  __hip_bfloat16 h2 = __float2bfloat16(a.z), h3 = __float2bfloat16(a.w);
  ushort4 u = make_ushort4(*(unsigned short*)&h0, *(unsigned short*)&h1,
                           *(unsigned short*)&h2, *(unsigned short*)&h3);
  const int b = row >> 9, s = row & 511;
  *(ushort4*)((unsigned short*)X + ((size_t)b * SP_ + s + 1) * D_ + threadIdx.x * 4) = u;
}

// ------------- inclusive cumsum of durations per batch; mel_len as float -----
__global__ __launch_bounds__(512) void scan_k(const int* __restrict__ dur,
                                              int* __restrict__ cum,
                                              float* __restrict__ mel_len) {
  __shared__ int sh[S_];
  const int b = blockIdx.x, t = threadIdx.x;
  sh[t] = dur[b * S_ + t];
  __syncthreads();
  for (int off = 1; off < S_; off <<= 1) {
    const int add = (t >= off) ? sh[t - off] : 0;
    __syncthreads();
    sh[t] += add;
    __syncthreads();
  }
  cum[b * S_ + t] = sh[t];
  if (t == S_ - 1) mel_len[b] = (float)sh[t];
}

// ------------- length regulate: out[b,pos,:] = valid ? X[b,idx,:] : 0 --------
__global__ __launch_bounds__(128) void gather_k(const __hip_bfloat16* __restrict__ X,
                                                const int* __restrict__ cum,
                                                float* __restrict__ out) {
  const int b   = blockIdx.x >> 12;    // T=4096 positions per batch
  const int pos = blockIdx.x & (T_ - 1);
  __shared__ int sidx, svalid;
  if (threadIdx.x == 0) {
    const int* c = cum + b * S_;
    int lo = 0, hi = S_;
    while (lo < hi) {                  // upper_bound: first c[i] > pos
      const int mid = (lo + hi) >> 1;
      if (c[mid] <= pos) lo = mid + 1; else hi = mid;
    }
    sidx = (lo < S_ - 1) ? lo : (S_ - 1);
    svalid = (pos < c[S_ - 1]) ? 1 : 0;
  }
  __syncthreads();
  float4 v = make_float4(0.f, 0.f, 0.f, 0.f);
  if (svalid) {
    const ushort4 u = *(const ushort4*)((const unsigned short*)X +
                        ((size_t)b * SP_ + sidx + 1) * D_ + threadIdx.x * 4);
    v = make_float4(bf2f(u.x), bf2f(u.y), bf2f(u.z), bf2f(u.w));
  }
  *(float4*)(out + ((size_t)b * T_ + pos) * D_ + threadIdx.x * 4) = v;
}

// ------------- mel_mask bool -> float ---------------------------------------
__global__ __launch_bounds__(256) void maskcopy_k(const unsigned char* __restrict__ m,
                                                  float* __restrict__ out) {
  const int i = blockIdx.x * 256 + threadIdx.x;
  out[i] = m[i] ? 1.f : 0.f;
}

extern "C" void kernel_launch(void* const* d_in, const int* in_sizes, int n_in,
                              void* d_out, int out_size, void* d_ws, size_t ws_size,
                              hipStream_t stream) {
  const float* x            = (const float*)d_in[0];
  const unsigned char* srcm = (const unsigned char*)d_in[1];
  const unsigned char* melm = (const unsigned char*)d_in[2];
  const float* pitch_truth  = (const float*)d_in[3];
  const float* energy_truth = (const float*)d_in[4];
  const int*   dur          = (const int*)d_in[5];
  const float* conv1_w = (const float*)d_in[6];
  const float* conv1_b = (const float*)d_in[7];
  const float* ln1_g   = (const float*)d_in[8];
  const float* ln1_b   = (const float*)d_in[9];
  const float* conv2_w = (const float*)d_in[10];
  const float* conv2_b = (const float*)d_in[11];
  const float* ln2_g   = (const float*)d_in[12];
  const float* ln2_b   = (const float*)d_in[13];
  const float* lin_w   = (const float*)d_in[14];
  const float* lin_b   = (const float*)d_in[15];
  const float* pitch_emb   = (const float*)d_in[16];
  const float* energy_emb  = (const float*)d_in[17];
  const float* pitch_bins  = (const float*)d_in[18];
  const float* energy_bins = (const float*)d_in[19];

  float* out      = (float*)d_out;
  float* x_out    = out;                               // 32*4096*512
  float* p_pitch  = out + (size_t)B_ * T_ * D_;
  float* p_energy = p_pitch + B_ * S_;
  float* p_dur    = p_energy + B_ * S_;
  float* p_mellen = p_dur + B_ * S_;
  float* p_mask   = p_mellen + B_;

  // ws: X (16.9MB) | P (16.9MB) | WT1 (4.7MB) | WT2 (4.7MB) | Yb (16.8MB)
  //     | cum (64KB)   total ~60MB
  __hip_bfloat16* X   = (__hip_bfloat16*)d_ws;
  __hip_bfloat16* P   = X + (size_t)B_ * SP_ * D_;
  __hip_bfloat16* WT1 = P + (size_t)B_ * SP_ * D_;
  __hip_bfloat16* WT2 = WT1 + (size_t)3 * F_ * KK_;
  __hip_bfloat16* Yb  = WT2 + (size_t)3 * F_ * KK_;
  int*  cum = (int*)(Yb + (size_t)B_ * S_ * F_);

  const dim3 blk512t(512), blk256(256), blk128(128);
  const dim3 rowGrid(B_ * S_);               // 16384
  const dim3 convGrid(512);                  // 128 M-tiles x 4 N-tiles

  zeropad_k<<<dim3(B_ * 2), blk128, 0, stream>>>(X, P);
  wtrans_k<<<dim3(6 * 24 * 8), blk256, 0, stream>>>(conv1_w, conv2_w, WT1, WT2);
  topad_k<<<rowGrid, blk128, 0, stream>>>(x, X);

  auto predictor = [&](int i, float* pred) {
    convmm_k<<<convGrid, blk256, 0, stream>>>(X, WT1 + (size_t)i * F_ * KK_, Yb);
    ln_pad_k<<<rowGrid, blk256, 0, stream>>>(Yb, conv1_b + (size_t)i * F_,
                                             ln1_g + (size_t)i * F_,
                                             ln1_b + (size_t)i * F_, P);
    convmm_k<<<convGrid, blk256, 0, stream>>>(P, WT2 + (size_t)i * F_ * KK_, Yb);
    lnlin_k<<<rowGrid, blk256, 0, stream>>>(Yb, conv2_b + (size_t)i * F_,
                                            ln2_g + (size_t)i * F_,
                                            ln2_b + (size_t)i * F_,
                                            lin_w + (size_t)i * F_, lin_b + i,
                                            srcm, pred);
  };

  predictor(0, p_pitch);
  addemb_k<<<rowGrid, blk128, 0, stream>>>(x, pitch_truth, pitch_bins, pitch_emb,
                                           nullptr, nullptr, nullptr, X);
  predictor(1, p_energy);
  addemb_k<<<rowGrid, blk128, 0, stream>>>(x, pitch_truth, pitch_bins, pitch_emb,
                                           energy_truth, energy_bins, energy_emb, X);
  predictor(2, p_dur);

  scan_k<<<dim3(B_), blk512t, 0, stream>>>(dur, cum, p_mellen);
  gather_k<<<dim3(B_ * T_), blk128, 0, stream>>>(X, cum, x_out);
  maskcopy_k<<<dim3((B_ * T_) / 256), blk256, 0, stream>>>(melm, p_mask);
}